// Round 13
// baseline (245.324 us; speedup 1.0000x reference)
//
#include <hip/hip_runtime.h>
#include <hip/hip_bf16.h>

#define NEG_SLOPE 0.2f
#define CAP 2560u   // LDS CSR capacity per 128-node bucket (mean 2046, +11 sigma)

typedef __attribute__((ext_vector_type(8))) short bf16x8;
typedef __attribute__((ext_vector_type(4))) float f32x4;

__device__ __forceinline__ float lrelu(float v) { return v > 0.0f ? v : NEG_SLOPE * v; }

__device__ __forceinline__ unsigned bf16pair(float a, float b) {
    unsigned ua = __float_as_uint(a), ub = __float_as_uint(b);
    ua = (ua + 0x7FFFu + ((ua >> 16) & 1u)) >> 16;
    ub = (ub + 0x7FFFu + ((ub >> 16) & 1u)) >> 16;
    return ua | (ub << 16);
}

__device__ __forceinline__ void gload16(const void* g, void* l) {
    __builtin_amdgcn_global_load_lds(
        (const __attribute__((address_space(1))) unsigned*)g,
        (__attribute__((address_space(3))) unsigned*)l, 16, 0, 0);
}

// ---------------- prep: x->xb bf16, W->Wt bf16 transposed, deg histogram ----
__global__ __launch_bounds__(256) void k_prep(const float* __restrict__ x,
                                              const float* __restrict__ W,
                                              const int* __restrict__ ei,
                                              unsigned* __restrict__ deg,
                                              unsigned* __restrict__ xb,
                                              unsigned short* __restrict__ Wt,
                                              int N, int E) {
    int gid = blockIdx.x * 256 + threadIdx.x;
    int gsz = gridDim.x * 256;
    int nf4 = N * 32;
    for (int i = gid; i < nf4; i += gsz) {
        float4 f = ((const float4*)x)[i];
        uint2 u;
        u.x = bf16pair(f.x, f.y);
        u.y = bf16pair(f.z, f.w);
        ((uint2*)xb)[i] = u;
    }
    if (gid < 16384) {
        int col = gid >> 7, k = gid & 127;
        float v = W[(size_t)k * 128 + col];
        unsigned u = __float_as_uint(v);
        u = (u + 0x7FFFu + ((u >> 16) & 1u)) >> 16;
        Wt[col * 128 + k] = (unsigned short)u;
    }
    for (int i = gid; i < E; i += gsz)
        atomicAdd(&deg[ei[(size_t)E + i]], 1u);
}

// ---- scan1: 128-node buckets; per-bucket exclusive scan + scatter-add total
__global__ __launch_bounds__(128) void k_scan1(const unsigned* __restrict__ deg,
                                               unsigned* __restrict__ part,
                                               unsigned* __restrict__ blockSums,
                                               unsigned* __restrict__ blockScan,
                                               int N, int NB) {
    __shared__ unsigned s[128];
    int t = threadIdx.x;
    int b = blockIdx.x;
    int i = b * 128 + t;
    unsigned v = (i < N) ? deg[i] : 0u;
    s[t] = v;
    __syncthreads();
    for (int off = 1; off < 128; off <<= 1) {
        unsigned a = (t >= off) ? s[t - off] : 0u;
        __syncthreads();
        s[t] += a;
        __syncthreads();
    }
    if (i < N) part[i] = s[t] - v;
    unsigned total = s[127];
    if (t == 0) blockSums[b] = total;
    for (int j = b + 1 + t; j < NB; j += 128)
        atomicAdd(&blockScan[j], total);
}

// ---------------- fused: bucket blocks (first NBK) + gemm blocks ------------
__global__ __launch_bounds__(512) void k_gembk(const unsigned* __restrict__ xb,
                                               const unsigned short* __restrict__ Wt,
                                               const float* __restrict__ att_src,
                                               const float* __restrict__ att_dst,
                                               unsigned* __restrict__ hb,
                                               float* __restrict__ a_src,
                                               float* __restrict__ a_dst,
                                               const int* __restrict__ ei,
                                               const unsigned* __restrict__ blockScan,
                                               unsigned* __restrict__ gcur,
                                               unsigned* __restrict__ ebuf,
                                               int N, int E, int NB, int NBK, int EPB) {
    __shared__ unsigned char sm[65536];
    int t = threadIdx.x;

    if ((int)blockIdx.x < NBK) {
        // ------------ bucket path: 4B packed entries src|(d&127)<<24 --------
        unsigned* cnt = (unsigned*)sm;            // NB <= 1024
        unsigned* cur2 = (unsigned*)(sm + 4096);
        unsigned* lbase = (unsigned*)(sm + 8192);
        int base = blockIdx.x * EPB;
        int lim = base + EPB;
        if (lim > E) lim = E;
        for (int j = t; j < NB; j += 512) { cnt[j] = 0u; cur2[j] = 0u; }
        __syncthreads();
        for (int i = base + t; i < lim; i += 512)
            atomicAdd(&cnt[(unsigned)ei[(size_t)E + i] >> 7], 1u);
        __syncthreads();
        for (int j = t; j < NB; j += 512) {
            unsigned c = cnt[j];
            lbase[j] = c ? (blockScan[j] + atomicAdd(&gcur[j], c)) : 0u;
        }
        __syncthreads();
        for (int i = base + t; i < lim; i += 512) {
            unsigned s = (unsigned)ei[i];
            unsigned d = (unsigned)ei[(size_t)E + i];
            unsigned b = d >> 7;
            unsigned k = atomicAdd(&cur2[b], 1u);
            ebuf[lbase[b] + k] = s | ((d & 127u) << 24);
        }
        return;
    }

    // ---------------- gemm path ----------------
    unsigned char* smA = sm;
    unsigned char* smB = sm + 32768;
    int w = t >> 6, lane = t & 63;
    int row0 = ((int)blockIdx.x - NBK) * 128;

#pragma unroll
    for (int it = 0; it < 4; ++it) {
        int L = w * 256 + it * 64 + lane;
        int r = L >> 4, c = L & 15;
        int cg = c ^ (r & 7);
        int gr = row0 + r;
        if (gr >= N) gr = N - 1;
        gload16(xb + (size_t)gr * 64 + cg * 4, smA + (size_t)w * 4096 + it * 1024);
        gload16((const unsigned*)Wt + r * 64 + cg * 4, smB + (size_t)w * 4096 + it * 1024);
    }
    __syncthreads();

    int lr = lane & 15, lg = lane >> 4;
    int ar = w * 16 + lr;

    f32x4 acc[8];
#pragma unroll
    for (int j = 0; j < 8; ++j)
#pragma unroll
        for (int q = 0; q < 4; ++q) acc[j][q] = 0.f;

#pragma unroll
    for (int kc = 0; kc < 4; ++kc) {
        bf16x8 av = *(const bf16x8*)&smA[ar * 256 + (((kc * 4 + lg) ^ (ar & 7)) * 16)];
        bf16x8 bv[8];
#pragma unroll
        for (int cf = 0; cf < 8; ++cf) {
            int bc = cf * 16 + lr;
            bv[cf] = *(const bf16x8*)&smB[bc * 256 + (((kc * 4 + lg) ^ (bc & 7)) * 16)];
        }
#pragma unroll
        for (int cf = 0; cf < 8; ++cf)
            acc[cf] = __builtin_amdgcn_mfma_f32_16x16x32_bf16(av, bv[cf], acc[cf], 0, 0, 0);
    }

    float att_s[8], att_d[8];
#pragma unroll
    for (int cf = 0; cf < 8; ++cf) {
        att_s[cf] = att_src[cf * 16 + lr];
        att_d[cf] = att_dst[cf * 16 + lr];
    }
#pragma unroll
    for (int reg = 0; reg < 4; ++reg) {
        int row = row0 + w * 16 + lg * 4 + reg;
        float ps[4], pd[4];
#pragma unroll
        for (int hh = 0; hh < 4; ++hh) {
            ps[hh] = acc[2 * hh][reg] * att_s[2 * hh] + acc[2 * hh + 1][reg] * att_s[2 * hh + 1];
            pd[hh] = acc[2 * hh][reg] * att_d[2 * hh] + acc[2 * hh + 1][reg] * att_d[2 * hh + 1];
        }
#pragma unroll
        for (int m = 1; m <= 8; m <<= 1) {
#pragma unroll
            for (int hh = 0; hh < 4; ++hh) {
                ps[hh] += __shfl_xor(ps[hh], m);
                pd[hh] += __shfl_xor(pd[hh], m);
            }
        }
        if (lr == 0 && row < N) {
            ((float4*)a_src)[row] = float4{ps[0], ps[1], ps[2], ps[3]};
            ((float4*)a_dst)[row] = float4{pd[0], pd[1], pd[2], pd[3]};
        }
    }

    unsigned char* scratch = smA + (size_t)w * 4096;
#pragma unroll
    for (int cf = 0; cf < 8; ++cf) {
#pragma unroll
        for (int reg = 0; reg < 4; ++reg) {
            float v = acc[cf][reg];
            float vo = __shfl_xor(v, 1);
            if (!(lane & 1))
                *(unsigned*)&scratch[(lg * 4 + reg) * 256 + cf * 32 + (lr >> 1) * 4] =
                    bf16pair(v, vo);
        }
    }
#pragma unroll
    for (int q = 0; q < 4; ++q) {
        uint4 u = *(const uint4*)&scratch[q * 1024 + lane * 16];
        int row = row0 + w * 16 + q * 4 + lg;
        if (row < N) ((uint4*)hb)[(size_t)row * 16 + lr] = u;
    }
}

// -------- fused place+gather: one 512-thread block per 128-node bucket ------
__global__ __launch_bounds__(512) void k_pg(const unsigned* __restrict__ hb,
                                            const unsigned* __restrict__ ebuf,
                                            const unsigned* __restrict__ blockScan,
                                            const unsigned* __restrict__ blockSums,
                                            const unsigned* __restrict__ part,
                                            const unsigned* __restrict__ deg,
                                            const float* __restrict__ a_src,
                                            const float* __restrict__ a_dst,
                                            const float* __restrict__ bias,
                                            float* __restrict__ out, int N) {
    __shared__ unsigned ls[CAP];        // src per edge slot
    __shared__ unsigned lpq[2 * CAP];   // p01,p23 per slot
    __shared__ unsigned curL[128];
    __shared__ unsigned ov[64];
    __shared__ unsigned oc;
    int t = threadIdx.x;
    int b = blockIdx.x;
    if (t < 128) curL[t] = 0u;
    if (t == 0) oc = 0u;
    __syncthreads();

    unsigned base = blockScan[b];
    unsigned cnt = blockSums[b];
    int nodeBase = b * 128;

    // phase 1: place this bucket's edges into LDS CSR, compute p (f16x4)
    for (unsigned i = t; i < cnt; i += 512) {
        unsigned e = ebuf[base + i];
        unsigned s = e & 0x00FFFFFFu;
        unsigned dLow = e >> 24;
        unsigned d = (unsigned)nodeBase + dLow;
        float4 as = ((const float4*)a_src)[s];
        float4 ad = ((const float4*)a_dst)[d];
        float p0 = __expf(lrelu(as.x + ad.x));
        float p1 = __expf(lrelu(as.y + ad.y));
        float p2 = __expf(lrelu(as.z + ad.z));
        float p3 = __expf(lrelu(as.w + ad.w));
        unsigned p01 = __builtin_bit_cast(unsigned, __builtin_amdgcn_cvt_pkrtz(p0, p1));
        unsigned p23 = __builtin_bit_cast(unsigned, __builtin_amdgcn_cvt_pkrtz(p2, p3));
        unsigned slot = part[d] + atomicAdd(&curL[dLow], 1u);
        if (slot < CAP) {
            ls[slot] = s;
            lpq[2 * slot] = p01;
            lpq[2 * slot + 1] = p23;
        } else {
            unsigned k = atomicAdd(&oc, 1u);
            if (k < 64u) ov[k] = e;
        }
    }
    __syncthreads();
    unsigned ocv = oc < 64u ? oc : 64u;

    // phase 2: gather; wave wv handles nodes wv, wv+8, ... (16 nodes each)
    int wv = t >> 6, lane = t & 63;
    int head = lane >> 4;
    unsigned sh = (head & 1) * 16;
    unsigned hsel = (head >> 1) & 1;
    for (int nn = wv; nn < 128; nn += 8) {
        int n = nodeBase + nn;
        if (n >= N) break;
        unsigned off = part[n];
        unsigned dg = deg[n];
        float ad_n = a_dst[n * 4 + head];
        float ax = 0.f, ay = 0.f, dsum = 0.f;
        for (unsigned b8 = 0; b8 < dg; b8 += 8) {
            unsigned se[8];
            float p[8];
#pragma unroll
            for (int i = 0; i < 8; ++i) {
                unsigned idx = b8 + i;
                if (idx >= dg) idx = dg - 1;
                unsigned li = off + idx;
                if (li >= CAP) li = 0;   // overflow slots handled in slow path
                se[i] = ls[li];
                unsigned pw = lpq[2 * li + hsel];
                float pp = (float)__builtin_bit_cast(_Float16, (unsigned short)(pw >> sh));
                p[i] = (b8 + i < dg && off + b8 + i < CAP) ? pp : 0.f;
            }
            unsigned u[8];
#pragma unroll
            for (int i = 0; i < 8; ++i) u[i] = hb[se[i] * 64u + (unsigned)lane];
#pragma unroll
            for (int i = 0; i < 8; ++i) {
                ax = fmaf(p[i], __uint_as_float(u[i] << 16), ax);
                ay = fmaf(p[i], __uint_as_float(u[i] & 0xFFFF0000u), ay);
                dsum += p[i];
            }
        }
        // overflow slow path (statistically never taken)
        for (unsigned j = 0; j < ocv; ++j) {
            unsigned e = ov[j];
            if ((int)(e >> 24) == nn) {
                unsigned s = e & 0x00FFFFFFu;
                float p = __expf(lrelu(a_src[s * 4 + head] + ad_n));
                unsigned u = hb[s * 64u + (unsigned)lane];
                ax = fmaf(p, __uint_as_float(u << 16), ax);
                ay = fmaf(p, __uint_as_float(u & 0xFFFF0000u), ay);
                dsum += p;
            }
        }
        // self loop
        float p_self = __expf(lrelu(a_src[n * 4 + head] + ad_n));
        unsigned us = hb[(unsigned)n * 64u + (unsigned)lane];
        ax = fmaf(p_self, __uint_as_float(us << 16), ax);
        ay = fmaf(p_self, __uint_as_float(us & 0xFFFF0000u), ay);
        dsum += p_self;
        float inv = 1.0f / dsum;
        float2 b2 = ((const float2*)bias)[lane];
        float ox = ax * inv + b2.x;
        float oy = ay * inv + b2.y;
        ox = ox > 0.f ? ox : (__expf(ox) - 1.0f);
        oy = oy > 0.f ? oy : (__expf(oy) - 1.0f);
        ((float2*)out)[(size_t)n * 64 + lane] = float2{ox, oy};
    }
}

extern "C" void kernel_launch(void* const* d_in, const int* in_sizes, int n_in,
                              void* d_out, int out_size, void* d_ws, size_t ws_size,
                              hipStream_t stream) {
    const float* x = (const float*)d_in[0];
    const int* ei = (const int*)d_in[1];
    const float* W = (const float*)d_in[2];
    const float* att_src = (const float*)d_in[3];
    const float* att_dst = (const float*)d_in[4];
    const float* bias = (const float*)d_in[5];
    int N = in_sizes[0] / 128;
    int E = in_sizes[1] / 2;
    int NB = (N + 127) / 128;  // 782 buckets of 128 nodes

    char* ws = (char*)d_ws;
    size_t o = 0;
    unsigned* hb = (unsigned*)(ws + o);   o += (size_t)N * 64 * 4;   // 25.6 MB
    float* a_src = (float*)(ws + o);      o += (size_t)N * 4 * 4;
    float* a_dst = (float*)(ws + o);      o += (size_t)N * 4 * 4;
    unsigned* ebuf = (unsigned*)(ws + o); o += (size_t)E * 4;        // 6.4 MB
    unsigned short* Wt = (unsigned short*)(ws + o); o += 128 * 128 * 2;
    unsigned* deg = (unsigned*)(ws + o);  o += (size_t)N * 4;        // ---- zeroed region
    unsigned* gcur = (unsigned*)(ws + o); o += 4096;                 // 1024 entries
    unsigned* blockScan = (unsigned*)(ws + o); o += 4096;            // ---- end zeroed
    unsigned* part = (unsigned*)(ws + o); o += (size_t)N * 4;
    unsigned* blockSums = (unsigned*)(ws + o); o += 4096;

    // xb (bf16 x) in d_out scratch: consumed by k_gembk, which completes
    // before k_pg writes d_out.
    unsigned* xb = (unsigned*)d_out;                          // 25.6 MB

    hipMemsetAsync(deg, 0, (size_t)N * 4 + 8192, stream);  // deg + gcur + blockScan

    k_prep<<<2048, 256, 0, stream>>>(x, W, ei, deg, xb, Wt, N, E);
    k_scan1<<<NB, 128, 0, stream>>>(deg, part, blockSums, blockScan, N, NB);
    int EPB = 16384;
    int NBK = (E + EPB - 1) / EPB;  // 98 bucket blocks
    int nbG = (N + 127) / 128;      // 782 gemm blocks
    k_gembk<<<NBK + nbG, 512, 0, stream>>>(xb, Wt, att_src, att_dst, hb, a_src, a_dst,
                                           ei, blockScan, gcur, ebuf, N, E, NB, NBK, EPB);
    k_pg<<<NB, 512, 0, stream>>>(hb, ebuf, blockScan, blockSums, part, deg,
                                 a_src, a_dst, bias, (float*)d_out, N);
}

// Round 14
// 240.628 us; speedup vs baseline: 1.0195x; 1.0195x over previous
//
#include <hip/hip_runtime.h>
#include <hip/hip_bf16.h>

#define NEG_SLOPE 0.2f

typedef __attribute__((ext_vector_type(8))) short bf16x8;
typedef __attribute__((ext_vector_type(4))) float f32x4;

__device__ __forceinline__ float lrelu(float v) { return v > 0.0f ? v : NEG_SLOPE * v; }

__device__ __forceinline__ unsigned bf16pair(float a, float b) {
    unsigned ua = __float_as_uint(a), ub = __float_as_uint(b);
    ua = (ua + 0x7FFFu + ((ua >> 16) & 1u)) >> 16;
    ub = (ub + 0x7FFFu + ((ub >> 16) & 1u)) >> 16;
    return ua | (ub << 16);
}

__device__ __forceinline__ void gload16(const void* g, void* l) {
    __builtin_amdgcn_global_load_lds(
        (const __attribute__((address_space(1))) unsigned*)g,
        (__attribute__((address_space(3))) unsigned*)l, 16, 0, 0);
}

// ---------------- prep: W->Wt bf16 transposed + deg histogram ----------------
__global__ __launch_bounds__(256) void k_prep(const float* __restrict__ W,
                                              const int* __restrict__ ei,
                                              unsigned* __restrict__ deg,
                                              unsigned short* __restrict__ Wt,
                                              int E) {
    int gid = blockIdx.x * 256 + threadIdx.x;
    int gsz = gridDim.x * 256;
    if (gid < 16384) {
        int col = gid >> 7, k = gid & 127;
        float v = W[(size_t)k * 128 + col];
        unsigned u = __float_as_uint(v);
        u = (u + 0x7FFFu + ((u >> 16) & 1u)) >> 16;
        Wt[col * 128 + k] = (unsigned short)u;
    }
    for (int i = gid; i < E; i += gsz)
        atomicAdd(&deg[ei[(size_t)E + i]], 1u);
}

// ---- scan1: per-block exclusive scan + scatter-add block total to later blocks
__global__ void k_scan1(const unsigned* __restrict__ deg, unsigned* __restrict__ part,
                        unsigned* __restrict__ blockSums, unsigned* __restrict__ blockScan,
                        int N, int NB) {
    __shared__ unsigned s[256];
    int t = threadIdx.x;
    int b = blockIdx.x;
    int i = b * 256 + t;
    unsigned v = (i < N) ? deg[i] : 0u;
    s[t] = v;
    __syncthreads();
    for (int off = 1; off < 256; off <<= 1) {
        unsigned a = (t >= off) ? s[t - off] : 0u;
        __syncthreads();
        s[t] += a;
        __syncthreads();
    }
    if (i < N) part[i] = s[t] - v;
    unsigned total = s[255];
    if (t == 0) blockSums[b] = total;
    for (int j = b + 1 + t; j < NB; j += 256)
        atomicAdd(&blockScan[j], total);
}

// ---------------- fused: bucket blocks (first NBK) + gemm blocks ------------
__global__ __launch_bounds__(512) void k_gembk(const float* __restrict__ x,
                                               const unsigned short* __restrict__ Wt,
                                               const float* __restrict__ att_src,
                                               const float* __restrict__ att_dst,
                                               unsigned* __restrict__ hb,
                                               float* __restrict__ a_src,
                                               float* __restrict__ a_dst,
                                               const int* __restrict__ ei,
                                               const unsigned* __restrict__ blockScan,
                                               unsigned* __restrict__ gcur,
                                               unsigned* __restrict__ ebuf,
                                               int N, int E, int NB, int NBK, int EPB) {
    __shared__ unsigned char sm[65536];
    int t = threadIdx.x;

    if ((int)blockIdx.x < NBK) {
        // ------------ bucket path: 4B packed entries src|(d&255)<<24 --------
        unsigned* cnt = (unsigned*)sm;
        unsigned* cur2 = (unsigned*)(sm + 2048);
        unsigned* lbase = (unsigned*)(sm + 4096);
        int base = blockIdx.x * EPB;
        int lim = base + EPB;
        if (lim > E) lim = E;
        for (int j = t; j < NB; j += 512) { cnt[j] = 0u; cur2[j] = 0u; }
        __syncthreads();
        for (int i = base + t; i < lim; i += 512)
            atomicAdd(&cnt[(unsigned)ei[(size_t)E + i] >> 8], 1u);
        __syncthreads();
        for (int j = t; j < NB; j += 512) {
            unsigned c = cnt[j];
            lbase[j] = c ? (blockScan[j] + atomicAdd(&gcur[j], c)) : 0u;
        }
        __syncthreads();
        for (int i = base + t; i < lim; i += 512) {
            unsigned s = (unsigned)ei[i];
            unsigned d = (unsigned)ei[(size_t)E + i];
            unsigned b = d >> 8;
            unsigned k = atomicAdd(&cur2[b], 1u);
            ebuf[lbase[b] + k] = s | ((d & 255u) << 24);
        }
        return;
    }

    // ---------------- gemm path ----------------
    unsigned char* smA = sm;
    unsigned char* smB = sm + 32768;
    int w = t >> 6, lane = t & 63;
    int row0 = ((int)blockIdx.x - NBK) * 128;

    // stage A: read x fp32 directly, convert, swizzled ds_write_b128
#pragma unroll
    for (int it = 0; it < 4; ++it) {
        int L = it * 512 + t;            // chunk 0..2047
        int r = L >> 4, c = L & 15;
        int gr = row0 + r;
        if (gr >= N) gr = N - 1;
        float4 f0 = ((const float4*)x)[(size_t)gr * 32 + c * 2];
        float4 f1 = ((const float4*)x)[(size_t)gr * 32 + c * 2 + 1];
        uint4 u;
        u.x = bf16pair(f0.x, f0.y);
        u.y = bf16pair(f0.z, f0.w);
        u.z = bf16pair(f1.x, f1.y);
        u.w = bf16pair(f1.z, f1.w);
        *(uint4*)&smA[r * 256 + ((c ^ (r & 7)) * 16)] = u;
    }
    // stage B: Wt (bf16) via global_load_lds, inverse-swizzled source
#pragma unroll
    for (int it = 0; it < 4; ++it) {
        int L = w * 256 + it * 64 + lane;
        int r = L >> 4, c = L & 15;
        int cg = c ^ (r & 7);
        gload16((const unsigned*)Wt + r * 64 + cg * 4, smB + (size_t)w * 4096 + it * 1024);
    }
    __syncthreads();

    int lr = lane & 15, lg = lane >> 4;
    int ar = w * 16 + lr;

    f32x4 acc[8];
#pragma unroll
    for (int j = 0; j < 8; ++j)
#pragma unroll
        for (int q = 0; q < 4; ++q) acc[j][q] = 0.f;

#pragma unroll
    for (int kc = 0; kc < 4; ++kc) {
        bf16x8 av = *(const bf16x8*)&smA[ar * 256 + (((kc * 4 + lg) ^ (ar & 7)) * 16)];
        bf16x8 bv[8];
#pragma unroll
        for (int cf = 0; cf < 8; ++cf) {
            int bc = cf * 16 + lr;
            bv[cf] = *(const bf16x8*)&smB[bc * 256 + (((kc * 4 + lg) ^ (bc & 7)) * 16)];
        }
#pragma unroll
        for (int cf = 0; cf < 8; ++cf)
            acc[cf] = __builtin_amdgcn_mfma_f32_16x16x32_bf16(av, bv[cf], acc[cf], 0, 0, 0);
    }

    float att_s[8], att_d[8];
#pragma unroll
    for (int cf = 0; cf < 8; ++cf) {
        att_s[cf] = att_src[cf * 16 + lr];
        att_d[cf] = att_dst[cf * 16 + lr];
    }
#pragma unroll
    for (int reg = 0; reg < 4; ++reg) {
        int row = row0 + w * 16 + lg * 4 + reg;
        float ps[4], pd[4];
#pragma unroll
        for (int hh = 0; hh < 4; ++hh) {
            ps[hh] = acc[2 * hh][reg] * att_s[2 * hh] + acc[2 * hh + 1][reg] * att_s[2 * hh + 1];
            pd[hh] = acc[2 * hh][reg] * att_d[2 * hh] + acc[2 * hh + 1][reg] * att_d[2 * hh + 1];
        }
#pragma unroll
        for (int m = 1; m <= 8; m <<= 1) {
#pragma unroll
            for (int hh = 0; hh < 4; ++hh) {
                ps[hh] += __shfl_xor(ps[hh], m);
                pd[hh] += __shfl_xor(pd[hh], m);
            }
        }
        if (lr == 0 && row < N) {
            ((float4*)a_src)[row] = float4{ps[0], ps[1], ps[2], ps[3]};
            ((float4*)a_dst)[row] = float4{pd[0], pd[1], pd[2], pd[3]};
        }
    }

    unsigned char* scratch = smA + (size_t)w * 4096;
#pragma unroll
    for (int cf = 0; cf < 8; ++cf) {
#pragma unroll
        for (int reg = 0; reg < 4; ++reg) {
            float v = acc[cf][reg];
            float vo = __shfl_xor(v, 1);
            if (!(lane & 1))
                *(unsigned*)&scratch[(lg * 4 + reg) * 256 + cf * 32 + (lr >> 1) * 4] =
                    bf16pair(v, vo);
        }
    }
#pragma unroll
    for (int q = 0; q < 4; ++q) {
        uint4 u = *(const uint4*)&scratch[q * 1024 + lane * 16];
        int row = row0 + w * 16 + q * 4 + lg;
        if (row < N) ((uint4*)hb)[(size_t)row * 16 + lr] = u;
    }
}

// ------- place within bucket: compute p (f16x4), write 16B CSR entries ------
__global__ __launch_bounds__(256) void k_place(const unsigned* __restrict__ ebuf,
                                               const unsigned* __restrict__ blockScan,
                                               const unsigned* __restrict__ blockSums,
                                               const unsigned* __restrict__ part,
                                               const float* __restrict__ a_src,
                                               const float* __restrict__ a_dst,
                                               uint4* __restrict__ csr) {
    __shared__ unsigned curL[256];
    int t = threadIdx.x;
    int b = blockIdx.x;
    curL[t] = 0u;
    __syncthreads();
    unsigned base = blockScan[b];
    unsigned cnt = blockSums[b];
    int nodeBase = b * 256;
    for (unsigned i = t; i < cnt; i += 256) {
        unsigned e = ebuf[base + i];
        unsigned s = e & 0x00FFFFFFu;
        unsigned dLow = e >> 24;
        unsigned d = (unsigned)nodeBase + dLow;
        unsigned r = atomicAdd(&curL[dLow], 1u);
        float4 as = ((const float4*)a_src)[s];
        float4 ad = ((const float4*)a_dst)[d];
        float p0 = __expf(lrelu(as.x + ad.x));
        float p1 = __expf(lrelu(as.y + ad.y));
        float p2 = __expf(lrelu(as.z + ad.z));
        float p3 = __expf(lrelu(as.w + ad.w));
        unsigned p01 = __builtin_bit_cast(unsigned, __builtin_amdgcn_cvt_pkrtz(p0, p1));
        unsigned p23 = __builtin_bit_cast(unsigned, __builtin_amdgcn_cvt_pkrtz(p2, p3));
        csr[base + part[d] + r] = uint4{s, p01, p23, 0u};
    }
}

// ---------------- gather: one wave per dst node, clamped 16-wide MLP ---------
__global__ __launch_bounds__(256) void k_gather(const unsigned* __restrict__ hb,
                                                const uint4* __restrict__ csr,
                                                const unsigned* __restrict__ part,
                                                const unsigned* __restrict__ blockScan,
                                                const unsigned* __restrict__ deg,
                                                const float* __restrict__ a_src,
                                                const float* __restrict__ a_dst,
                                                const float* __restrict__ bias,
                                                float* __restrict__ out, int N) {
    int n = (int)((blockIdx.x * 256 + threadIdx.x) >> 6);
    int lane = threadIdx.x & 63;
    if (n >= N) return;
    int head = lane >> 4;
    unsigned sh = (head & 1) * 16;
    unsigned off = part[n] + blockScan[n >> 8];
    unsigned end = off + deg[n];
    float ax = 0.f, ay = 0.f, dsum = 0.f;
    for (unsigned b = off; b < end; b += 16) {
        uint4 e[16];
#pragma unroll
        for (int i = 0; i < 16; ++i) e[i] = csr[min(b + i, end - 1)];
        float p[16];
#pragma unroll
        for (int i = 0; i < 16; ++i) {
            unsigned pw = (head & 2) ? e[i].z : e[i].y;
            float pp = (float)__builtin_bit_cast(_Float16, (unsigned short)(pw >> sh));
            p[i] = (b + i < end) ? pp : 0.f;
        }
        unsigned u[16];
#pragma unroll
        for (int i = 0; i < 16; ++i) u[i] = hb[e[i].x * 64u + (unsigned)lane];
#pragma unroll
        for (int i = 0; i < 16; ++i) {
            ax = fmaf(p[i], __uint_as_float(u[i] << 16), ax);
            ay = fmaf(p[i], __uint_as_float(u[i] & 0xFFFF0000u), ay);
            dsum += p[i];
        }
    }
    float p_self = __expf(lrelu(a_src[n * 4 + head] + a_dst[n * 4 + head]));
    unsigned us = hb[(unsigned)n * 64u + (unsigned)lane];
    ax = fmaf(p_self, __uint_as_float(us << 16), ax);
    ay = fmaf(p_self, __uint_as_float(us & 0xFFFF0000u), ay);
    dsum += p_self;
    float inv = 1.0f / dsum;
    float2 b2 = ((const float2*)bias)[lane];
    float ox = ax * inv + b2.x;
    float oy = ay * inv + b2.y;
    ox = ox > 0.f ? ox : (__expf(ox) - 1.0f);
    oy = oy > 0.f ? oy : (__expf(oy) - 1.0f);
    ((float2*)out)[(size_t)n * 64 + lane] = float2{ox, oy};
}

extern "C" void kernel_launch(void* const* d_in, const int* in_sizes, int n_in,
                              void* d_out, int out_size, void* d_ws, size_t ws_size,
                              hipStream_t stream) {
    const float* x = (const float*)d_in[0];
    const int* ei = (const int*)d_in[1];
    const float* W = (const float*)d_in[2];
    const float* att_src = (const float*)d_in[3];
    const float* att_dst = (const float*)d_in[4];
    const float* bias = (const float*)d_in[5];
    int N = in_sizes[0] / 128;
    int E = in_sizes[1] / 2;
    int NB = (N + 255) / 256;  // 391 buckets of 256 nodes

    char* ws = (char*)d_ws;
    size_t o = 0;
    unsigned* hb = (unsigned*)(ws + o);   o += (size_t)N * 64 * 4;   // 25.6 MB
    float* a_src = (float*)(ws + o);      o += (size_t)N * 4 * 4;
    float* a_dst = (float*)(ws + o);      o += (size_t)N * 4 * 4;
    uint4* csr = (uint4*)(ws + o);        o += (size_t)E * 16;       // 25.6 MB
    unsigned* ebuf = (unsigned*)(ws + o); o += (size_t)E * 4;        // 6.4 MB
    unsigned short* Wt = (unsigned short*)(ws + o); o += 128 * 128 * 2;
    unsigned* deg = (unsigned*)(ws + o);  o += (size_t)N * 4;        // ---- zeroed region
    unsigned* gcur = (unsigned*)(ws + o); o += 2048;
    unsigned* blockScan = (unsigned*)(ws + o); o += 2048;            // ---- end zeroed
    unsigned* part = (unsigned*)(ws + o); o += (size_t)N * 4;
    unsigned* blockSums = (unsigned*)(ws + o); o += 2048;

    hipMemsetAsync(deg, 0, (size_t)N * 4 + 4096, stream);  // deg + gcur + blockScan

    k_prep<<<2048, 256, 0, stream>>>(W, ei, deg, Wt, E);
    k_scan1<<<NB, 256, 0, stream>>>(deg, part, blockSums, blockScan, N, NB);
    int EPB = 16384;
    int NBK = (E + EPB - 1) / EPB;  // 98 bucket blocks
    int nbG = (N + 127) / 128;      // 782 gemm blocks
    k_gembk<<<NBK + nbG, 512, 0, stream>>>(x, Wt, att_src, att_dst, hb, a_src, a_dst,
                                           ei, blockScan, gcur, ebuf, N, E, NB, NBK, EPB);
    k_place<<<NB, 256, 0, stream>>>(ebuf, blockScan, blockSums, part, a_src, a_dst, csr);
    k_gather<<<(N * 64 + 255) / 256, 256, 0, stream>>>(hb, csr, part, blockScan, deg,
                                                       a_src, a_dst, bias, (float*)d_out, N);
}

// Round 15
// 212.304 us; speedup vs baseline: 1.1555x; 1.1334x over previous
//
#include <hip/hip_runtime.h>
#include <hip/hip_bf16.h>

#define NEG_SLOPE 0.2f

typedef __attribute__((ext_vector_type(8))) short bf16x8;
typedef __attribute__((ext_vector_type(4))) float f32x4;

__device__ __forceinline__ float lrelu(float v) { return v > 0.0f ? v : NEG_SLOPE * v; }

__device__ __forceinline__ unsigned bf16pair(float a, float b) {
    unsigned ua = __float_as_uint(a), ub = __float_as_uint(b);
    ua = (ua + 0x7FFFu + ((ua >> 16) & 1u)) >> 16;
    ub = (ub + 0x7FFFu + ((ub >> 16) & 1u)) >> 16;
    return ua | (ub << 16);
}

__device__ __forceinline__ void gload16(const void* g, void* l) {
    __builtin_amdgcn_global_load_lds(
        (const __attribute__((address_space(1))) unsigned*)g,
        (__attribute__((address_space(3))) unsigned*)l, 16, 0, 0);
}

// ---------------- prep: W->Wt bf16 transposed + deg histogram ----------------
__global__ __launch_bounds__(256) void k_prep(const float* __restrict__ W,
                                              const int* __restrict__ ei,
                                              unsigned* __restrict__ deg,
                                              unsigned short* __restrict__ Wt,
                                              int E) {
    int gid = blockIdx.x * 256 + threadIdx.x;
    int gsz = gridDim.x * 256;
    if (gid < 16384) {
        int col = gid >> 7, k = gid & 127;
        float v = W[(size_t)k * 128 + col];
        unsigned u = __float_as_uint(v);
        u = (u + 0x7FFFu + ((u >> 16) & 1u)) >> 16;
        Wt[col * 128 + k] = (unsigned short)u;
    }
    for (int i = gid; i < E; i += gsz)
        atomicAdd(&deg[ei[(size_t)E + i]], 1u);
}

// ---- scan1: per-block exclusive scan + scatter-add block total to later blocks
__global__ void k_scan1(const unsigned* __restrict__ deg, unsigned* __restrict__ part,
                        unsigned* __restrict__ blockSums, unsigned* __restrict__ blockScan,
                        int N, int NB) {
    __shared__ unsigned s[256];
    int t = threadIdx.x;
    int b = blockIdx.x;
    int i = b * 256 + t;
    unsigned v = (i < N) ? deg[i] : 0u;
    s[t] = v;
    __syncthreads();
    for (int off = 1; off < 256; off <<= 1) {
        unsigned a = (t >= off) ? s[t - off] : 0u;
        __syncthreads();
        s[t] += a;
        __syncthreads();
    }
    if (i < N) part[i] = s[t] - v;
    unsigned total = s[255];
    if (t == 0) blockSums[b] = total;
    for (int j = b + 1 + t; j < NB; j += 256)
        atomicAdd(&blockScan[j], total);
}

// ---------------- fused: bucket blocks (first NBK) + gemm blocks ------------
__global__ __launch_bounds__(512) void k_gembk(const float* __restrict__ x,
                                               const unsigned short* __restrict__ Wt,
                                               const float* __restrict__ att_src,
                                               const float* __restrict__ att_dst,
                                               unsigned* __restrict__ hb,
                                               float* __restrict__ a_src,
                                               float* __restrict__ a_dst,
                                               const int* __restrict__ ei,
                                               const unsigned* __restrict__ blockScan,
                                               unsigned* __restrict__ gcur,
                                               unsigned* __restrict__ ebuf,
                                               int N, int E, int NB, int NBK, int EPB) {
    __shared__ unsigned char sm[65536];
    int t = threadIdx.x;

    if ((int)blockIdx.x < NBK) {
        // ------------ bucket path: 4B packed entries src|(d&255)<<24 --------
        unsigned* cnt = (unsigned*)sm;
        unsigned* cur2 = (unsigned*)(sm + 2048);
        unsigned* lbase = (unsigned*)(sm + 4096);
        int base = blockIdx.x * EPB;
        int lim = base + EPB;
        if (lim > E) lim = E;
        for (int j = t; j < NB; j += 512) { cnt[j] = 0u; cur2[j] = 0u; }
        __syncthreads();
        for (int i = base + t; i < lim; i += 512)
            atomicAdd(&cnt[(unsigned)ei[(size_t)E + i] >> 8], 1u);
        __syncthreads();
        for (int j = t; j < NB; j += 512) {
            unsigned c = cnt[j];
            lbase[j] = c ? (blockScan[j] + atomicAdd(&gcur[j], c)) : 0u;
        }
        __syncthreads();
        for (int i = base + t; i < lim; i += 512) {
            unsigned s = (unsigned)ei[i];
            unsigned d = (unsigned)ei[(size_t)E + i];
            unsigned b = d >> 8;
            unsigned k = atomicAdd(&cur2[b], 1u);
            ebuf[lbase[b] + k] = s | ((d & 255u) << 24);
        }
        return;
    }

    // ---------------- gemm path ----------------
    unsigned char* smA = sm;
    unsigned char* smB = sm + 32768;
    int w = t >> 6, lane = t & 63;
    int row0 = ((int)blockIdx.x - NBK) * 128;

    // stage A: read x fp32 directly, convert, swizzled ds_write_b128
#pragma unroll
    for (int it = 0; it < 4; ++it) {
        int L = it * 512 + t;            // chunk 0..2047
        int r = L >> 4, c = L & 15;
        int gr = row0 + r;
        if (gr >= N) gr = N - 1;
        float4 f0 = ((const float4*)x)[(size_t)gr * 32 + c * 2];
        float4 f1 = ((const float4*)x)[(size_t)gr * 32 + c * 2 + 1];
        uint4 u;
        u.x = bf16pair(f0.x, f0.y);
        u.y = bf16pair(f0.z, f0.w);
        u.z = bf16pair(f1.x, f1.y);
        u.w = bf16pair(f1.z, f1.w);
        *(uint4*)&smA[r * 256 + ((c ^ (r & 7)) * 16)] = u;
    }
    // stage B: Wt (bf16) via global_load_lds, inverse-swizzled source
#pragma unroll
    for (int it = 0; it < 4; ++it) {
        int L = w * 256 + it * 64 + lane;
        int r = L >> 4, c = L & 15;
        int cg = c ^ (r & 7);
        gload16((const unsigned*)Wt + r * 64 + cg * 4, smB + (size_t)w * 4096 + it * 1024);
    }
    __syncthreads();

    int lr = lane & 15, lg = lane >> 4;
    int ar = w * 16 + lr;

    f32x4 acc[8];
#pragma unroll
    for (int j = 0; j < 8; ++j)
#pragma unroll
        for (int q = 0; q < 4; ++q) acc[j][q] = 0.f;

#pragma unroll
    for (int kc = 0; kc < 4; ++kc) {
        bf16x8 av = *(const bf16x8*)&smA[ar * 256 + (((kc * 4 + lg) ^ (ar & 7)) * 16)];
        bf16x8 bv[8];
#pragma unroll
        for (int cf = 0; cf < 8; ++cf) {
            int bc = cf * 16 + lr;
            bv[cf] = *(const bf16x8*)&smB[bc * 256 + (((kc * 4 + lg) ^ (bc & 7)) * 16)];
        }
#pragma unroll
        for (int cf = 0; cf < 8; ++cf)
            acc[cf] = __builtin_amdgcn_mfma_f32_16x16x32_bf16(av, bv[cf], acc[cf], 0, 0, 0);
    }

    float att_s[8], att_d[8];
#pragma unroll
    for (int cf = 0; cf < 8; ++cf) {
        att_s[cf] = att_src[cf * 16 + lr];
        att_d[cf] = att_dst[cf * 16 + lr];
    }
#pragma unroll
    for (int reg = 0; reg < 4; ++reg) {
        int row = row0 + w * 16 + lg * 4 + reg;
        float ps[4], pd[4];
#pragma unroll
        for (int hh = 0; hh < 4; ++hh) {
            ps[hh] = acc[2 * hh][reg] * att_s[2 * hh] + acc[2 * hh + 1][reg] * att_s[2 * hh + 1];
            pd[hh] = acc[2 * hh][reg] * att_d[2 * hh] + acc[2 * hh + 1][reg] * att_d[2 * hh + 1];
        }
#pragma unroll
        for (int m = 1; m <= 8; m <<= 1) {
#pragma unroll
            for (int hh = 0; hh < 4; ++hh) {
                ps[hh] += __shfl_xor(ps[hh], m);
                pd[hh] += __shfl_xor(pd[hh], m);
            }
        }
        if (lr == 0 && row < N) {
            ((float4*)a_src)[row] = float4{ps[0], ps[1], ps[2], ps[3]};
            ((float4*)a_dst)[row] = float4{pd[0], pd[1], pd[2], pd[3]};
        }
    }

    unsigned char* scratch = smA + (size_t)w * 4096;
#pragma unroll
    for (int cf = 0; cf < 8; ++cf) {
#pragma unroll
        for (int reg = 0; reg < 4; ++reg) {
            float v = acc[cf][reg];
            float vo = __shfl_xor(v, 1);
            if (!(lane & 1))
                *(unsigned*)&scratch[(lg * 4 + reg) * 256 + cf * 32 + (lr >> 1) * 4] =
                    bf16pair(v, vo);
        }
    }
#pragma unroll
    for (int q = 0; q < 4; ++q) {
        uint4 u = *(const uint4*)&scratch[q * 1024 + lane * 16];
        int row = row0 + w * 16 + q * 4 + lg;
        if (row < N) ((uint4*)hb)[(size_t)row * 16 + lr] = u;
    }
}

// ------- place within bucket: pure permutation, 4B csr_src entries ----------
__global__ __launch_bounds__(256) void k_place(const unsigned* __restrict__ ebuf,
                                               const unsigned* __restrict__ blockScan,
                                               const unsigned* __restrict__ blockSums,
                                               const unsigned* __restrict__ part,
                                               unsigned* __restrict__ csr_src) {
    __shared__ unsigned curL[256];
    int t = threadIdx.x;
    int b = blockIdx.x;
    curL[t] = 0u;
    __syncthreads();
    unsigned base = blockScan[b];
    unsigned cnt = blockSums[b];
    const unsigned* __restrict__ partB = part + b * 256;
    for (unsigned i = t; i < cnt; i += 256) {
        unsigned e = ebuf[base + i];
        unsigned s = e & 0x00FFFFFFu;
        unsigned dLow = e >> 24;
        unsigned r = atomicAdd(&curL[dLow], 1u);
        csr_src[base + partB[dLow] + r] = s;
    }
}

// ---------------- gather: one wave per dst node, recompute p, 8-wide MLP ----
__global__ __launch_bounds__(256) void k_gather(const unsigned* __restrict__ hb,
                                                const unsigned* __restrict__ csr_src,
                                                const unsigned* __restrict__ part,
                                                const unsigned* __restrict__ blockScan,
                                                const unsigned* __restrict__ deg,
                                                const float* __restrict__ a_src,
                                                const float* __restrict__ a_dst,
                                                const float* __restrict__ bias,
                                                float* __restrict__ out, int N) {
    int n = (int)((blockIdx.x * 256 + threadIdx.x) >> 6);
    int lane = threadIdx.x & 63;
    if (n >= N) return;
    int head = lane >> 4;
    unsigned off = part[n] + blockScan[n >> 8];
    unsigned end = off + deg[n];
    float ad_n = a_dst[n * 4 + head];
    float ax = 0.f, ay = 0.f, dsum = 0.f;
    for (unsigned b = off; b < end; b += 8) {
        unsigned ss[8];
#pragma unroll
        for (int i = 0; i < 8; ++i) {
            unsigned idx = b + i;
            if (idx >= end) idx = end - 1;
            ss[i] = csr_src[idx];
        }
        float as[8];
        unsigned u[8];
#pragma unroll
        for (int i = 0; i < 8; ++i) {
            as[i] = a_src[ss[i] * 4 + head];
            u[i] = hb[ss[i] * 64u + (unsigned)lane];
        }
#pragma unroll
        for (int i = 0; i < 8; ++i) {
            float p = __expf(lrelu(as[i] + ad_n));
            p = (b + i < end) ? p : 0.f;
            ax = fmaf(p, __uint_as_float(u[i] << 16), ax);
            ay = fmaf(p, __uint_as_float(u[i] & 0xFFFF0000u), ay);
            dsum += p;
        }
    }
    // self loop
    float p_self = __expf(lrelu(a_src[n * 4 + head] + ad_n));
    unsigned us = hb[(unsigned)n * 64u + (unsigned)lane];
    ax = fmaf(p_self, __uint_as_float(us << 16), ax);
    ay = fmaf(p_self, __uint_as_float(us & 0xFFFF0000u), ay);
    dsum += p_self;
    float inv = 1.0f / dsum;
    float2 b2 = ((const float2*)bias)[lane];
    float ox = ax * inv + b2.x;
    float oy = ay * inv + b2.y;
    ox = ox > 0.f ? ox : (__expf(ox) - 1.0f);
    oy = oy > 0.f ? oy : (__expf(oy) - 1.0f);
    ((float2*)out)[(size_t)n * 64 + lane] = float2{ox, oy};
}

extern "C" void kernel_launch(void* const* d_in, const int* in_sizes, int n_in,
                              void* d_out, int out_size, void* d_ws, size_t ws_size,
                              hipStream_t stream) {
    const float* x = (const float*)d_in[0];
    const int* ei = (const int*)d_in[1];
    const float* W = (const float*)d_in[2];
    const float* att_src = (const float*)d_in[3];
    const float* att_dst = (const float*)d_in[4];
    const float* bias = (const float*)d_in[5];
    int N = in_sizes[0] / 128;
    int E = in_sizes[1] / 2;
    int NB = (N + 255) / 256;  // 391 buckets of 256 nodes

    char* ws = (char*)d_ws;
    size_t o = 0;
    unsigned* hb = (unsigned*)(ws + o);   o += (size_t)N * 64 * 4;   // 25.6 MB
    float* a_src = (float*)(ws + o);      o += (size_t)N * 4 * 4;
    float* a_dst = (float*)(ws + o);      o += (size_t)N * 4 * 4;
    unsigned* csr_src = (unsigned*)(ws + o); o += (size_t)E * 4;     // 6.4 MB
    unsigned* ebuf = (unsigned*)(ws + o); o += (size_t)E * 4;        // 6.4 MB
    unsigned short* Wt = (unsigned short*)(ws + o); o += 128 * 128 * 2;
    unsigned* deg = (unsigned*)(ws + o);  o += (size_t)N * 4;        // ---- zeroed region
    unsigned* gcur = (unsigned*)(ws + o); o += 2048;
    unsigned* blockScan = (unsigned*)(ws + o); o += 2048;            // ---- end zeroed
    unsigned* part = (unsigned*)(ws + o); o += (size_t)N * 4;
    unsigned* blockSums = (unsigned*)(ws + o); o += 2048;

    hipMemsetAsync(deg, 0, (size_t)N * 4 + 4096, stream);  // deg + gcur + blockScan

    k_prep<<<2048, 256, 0, stream>>>(W, ei, deg, Wt, E);
    k_scan1<<<NB, 256, 0, stream>>>(deg, part, blockSums, blockScan, N, NB);
    int EPB = 16384;
    int NBK = (E + EPB - 1) / EPB;  // 98 bucket blocks
    int nbG = (N + 127) / 128;      // 782 gemm blocks
    k_gembk<<<NBK + nbG, 512, 0, stream>>>(x, Wt, att_src, att_dst, hb, a_src, a_dst,
                                           ei, blockScan, gcur, ebuf, N, E, NB, NBK, EPB);
    k_place<<<NB, 256, 0, stream>>>(ebuf, blockScan, blockSums, part, csr_src);
    k_gather<<<(N * 64 + 255) / 256, 256, 0, stream>>>(hb, csr_src, part, blockScan, deg,
                                                       a_src, a_dst, bias, (float*)d_out, N);
}

// Round 16
// 210.715 us; speedup vs baseline: 1.1642x; 1.0075x over previous
//
#include <hip/hip_runtime.h>
#include <hip/hip_bf16.h>

#define NEG_SLOPE 0.2f

typedef __attribute__((ext_vector_type(8))) short bf16x8;
typedef __attribute__((ext_vector_type(4))) float f32x4;

__device__ __forceinline__ float lrelu(float v) { return v > 0.0f ? v : NEG_SLOPE * v; }

__device__ __forceinline__ unsigned bf16pair(float a, float b) {
    unsigned ua = __float_as_uint(a), ub = __float_as_uint(b);
    ua = (ua + 0x7FFFu + ((ua >> 16) & 1u)) >> 16;
    ub = (ub + 0x7FFFu + ((ub >> 16) & 1u)) >> 16;
    return ua | (ub << 16);
}

__device__ __forceinline__ void gload16(const void* g, void* l) {
    __builtin_amdgcn_global_load_lds(
        (const __attribute__((address_space(1))) unsigned*)g,
        (__attribute__((address_space(3))) unsigned*)l, 16, 0, 0);
}

// ---------------- prep: W->Wt bf16 transposed + deg histogram ----------------
__global__ __launch_bounds__(256) void k_prep(const float* __restrict__ W,
                                              const int* __restrict__ ei,
                                              unsigned* __restrict__ deg,
                                              unsigned short* __restrict__ Wt,
                                              int E) {
    int gid = blockIdx.x * 256 + threadIdx.x;
    int gsz = gridDim.x * 256;
    if (gid < 16384) {
        int col = gid >> 7, k = gid & 127;
        float v = W[(size_t)k * 128 + col];
        unsigned u = __float_as_uint(v);
        u = (u + 0x7FFFu + ((u >> 16) & 1u)) >> 16;
        Wt[col * 128 + k] = (unsigned short)u;
    }
    for (int i = gid; i < E; i += gsz)
        atomicAdd(&deg[ei[(size_t)E + i]], 1u);
}

// ---- scan1: per-block exclusive scan + scatter-add block total to later blocks
__global__ void k_scan1(const unsigned* __restrict__ deg, unsigned* __restrict__ part,
                        unsigned* __restrict__ blockSums, unsigned* __restrict__ blockScan,
                        int N, int NB) {
    __shared__ unsigned s[256];
    int t = threadIdx.x;
    int b = blockIdx.x;
    int i = b * 256 + t;
    unsigned v = (i < N) ? deg[i] : 0u;
    s[t] = v;
    __syncthreads();
    for (int off = 1; off < 256; off <<= 1) {
        unsigned a = (t >= off) ? s[t - off] : 0u;
        __syncthreads();
        s[t] += a;
        __syncthreads();
    }
    if (i < N) part[i] = s[t] - v;
    unsigned total = s[255];
    if (t == 0) blockSums[b] = total;
    for (int j = b + 1 + t; j < NB; j += 256)
        atomicAdd(&blockScan[j], total);
}

// ---------------- fused: bucket blocks (first NBK) + gemm blocks ------------
__global__ __launch_bounds__(512) void k_gembk(const float* __restrict__ x,
                                               const unsigned short* __restrict__ Wt,
                                               const float* __restrict__ att_src,
                                               const float* __restrict__ att_dst,
                                               unsigned* __restrict__ hb,
                                               float* __restrict__ a_src,
                                               float* __restrict__ a_dst,
                                               const int* __restrict__ ei,
                                               const unsigned* __restrict__ blockScan,
                                               unsigned* __restrict__ gcur,
                                               unsigned* __restrict__ ebuf,
                                               int N, int E, int NB, int NBK, int EPB) {
    __shared__ unsigned char sm[65536];
    int t = threadIdx.x;

    if ((int)blockIdx.x < NBK) {
        // ------------ bucket path: 4B packed entries src|(d&255)<<24 --------
        unsigned* cnt = (unsigned*)sm;
        unsigned* cur2 = (unsigned*)(sm + 2048);
        unsigned* lbase = (unsigned*)(sm + 4096);
        int base = blockIdx.x * EPB;
        int lim = base + EPB;
        if (lim > E) lim = E;
        for (int j = t; j < NB; j += 512) { cnt[j] = 0u; cur2[j] = 0u; }
        __syncthreads();
        for (int i = base + t; i < lim; i += 512)
            atomicAdd(&cnt[(unsigned)ei[(size_t)E + i] >> 8], 1u);
        __syncthreads();
        for (int j = t; j < NB; j += 512) {
            unsigned c = cnt[j];
            lbase[j] = c ? (blockScan[j] + atomicAdd(&gcur[j], c)) : 0u;
        }
        __syncthreads();
        for (int i = base + t; i < lim; i += 512) {
            unsigned s = (unsigned)ei[i];
            unsigned d = (unsigned)ei[(size_t)E + i];
            unsigned b = d >> 8;
            unsigned k = atomicAdd(&cur2[b], 1u);
            ebuf[lbase[b] + k] = s | ((d & 255u) << 24);
        }
        return;
    }

    // ---------------- gemm path ----------------
    unsigned char* smA = sm;
    unsigned char* smB = sm + 32768;
    int w = t >> 6, lane = t & 63;
    int row0 = ((int)blockIdx.x - NBK) * 128;

    // stage A: read x fp32 directly, convert, swizzled ds_write_b128
#pragma unroll
    for (int it = 0; it < 4; ++it) {
        int L = it * 512 + t;            // chunk 0..2047
        int r = L >> 4, c = L & 15;
        int gr = row0 + r;
        if (gr >= N) gr = N - 1;
        float4 f0 = ((const float4*)x)[(size_t)gr * 32 + c * 2];
        float4 f1 = ((const float4*)x)[(size_t)gr * 32 + c * 2 + 1];
        uint4 u;
        u.x = bf16pair(f0.x, f0.y);
        u.y = bf16pair(f0.z, f0.w);
        u.z = bf16pair(f1.x, f1.y);
        u.w = bf16pair(f1.z, f1.w);
        *(uint4*)&smA[r * 256 + ((c ^ (r & 7)) * 16)] = u;
    }
    // stage B: Wt (bf16) via global_load_lds, inverse-swizzled source
#pragma unroll
    for (int it = 0; it < 4; ++it) {
        int L = w * 256 + it * 64 + lane;
        int r = L >> 4, c = L & 15;
        int cg = c ^ (r & 7);
        gload16((const unsigned*)Wt + r * 64 + cg * 4, smB + (size_t)w * 4096 + it * 1024);
    }
    __syncthreads();

    int lr = lane & 15, lg = lane >> 4;
    int ar = w * 16 + lr;

    f32x4 acc[8];
#pragma unroll
    for (int j = 0; j < 8; ++j)
#pragma unroll
        for (int q = 0; q < 4; ++q) acc[j][q] = 0.f;

#pragma unroll
    for (int kc = 0; kc < 4; ++kc) {
        bf16x8 av = *(const bf16x8*)&smA[ar * 256 + (((kc * 4 + lg) ^ (ar & 7)) * 16)];
        bf16x8 bv[8];
#pragma unroll
        for (int cf = 0; cf < 8; ++cf) {
            int bc = cf * 16 + lr;
            bv[cf] = *(const bf16x8*)&smB[bc * 256 + (((kc * 4 + lg) ^ (bc & 7)) * 16)];
        }
#pragma unroll
        for (int cf = 0; cf < 8; ++cf)
            acc[cf] = __builtin_amdgcn_mfma_f32_16x16x32_bf16(av, bv[cf], acc[cf], 0, 0, 0);
    }

    float att_s[8], att_d[8];
#pragma unroll
    for (int cf = 0; cf < 8; ++cf) {
        att_s[cf] = att_src[cf * 16 + lr];
        att_d[cf] = att_dst[cf * 16 + lr];
    }
#pragma unroll
    for (int reg = 0; reg < 4; ++reg) {
        int row = row0 + w * 16 + lg * 4 + reg;
        float ps[4], pd[4];
#pragma unroll
        for (int hh = 0; hh < 4; ++hh) {
            ps[hh] = acc[2 * hh][reg] * att_s[2 * hh] + acc[2 * hh + 1][reg] * att_s[2 * hh + 1];
            pd[hh] = acc[2 * hh][reg] * att_d[2 * hh] + acc[2 * hh + 1][reg] * att_d[2 * hh + 1];
        }
#pragma unroll
        for (int m = 1; m <= 8; m <<= 1) {
#pragma unroll
            for (int hh = 0; hh < 4; ++hh) {
                ps[hh] += __shfl_xor(ps[hh], m);
                pd[hh] += __shfl_xor(pd[hh], m);
            }
        }
        if (lr == 0 && row < N) {
            ((float4*)a_src)[row] = float4{ps[0], ps[1], ps[2], ps[3]};
            ((float4*)a_dst)[row] = float4{pd[0], pd[1], pd[2], pd[3]};
        }
    }

    unsigned char* scratch = smA + (size_t)w * 4096;
#pragma unroll
    for (int cf = 0; cf < 8; ++cf) {
#pragma unroll
        for (int reg = 0; reg < 4; ++reg) {
            float v = acc[cf][reg];
            float vo = __shfl_xor(v, 1);
            if (!(lane & 1))
                *(unsigned*)&scratch[(lg * 4 + reg) * 256 + cf * 32 + (lr >> 1) * 4] =
                    bf16pair(v, vo);
        }
    }
#pragma unroll
    for (int q = 0; q < 4; ++q) {
        uint4 u = *(const uint4*)&scratch[q * 1024 + lane * 16];
        int row = row0 + w * 16 + q * 4 + lg;
        if (row < N) ((uint4*)hb)[(size_t)row * 16 + lr] = u;
    }
}

// ------- place within bucket: pure permutation, 4B csr_src entries ----------
__global__ __launch_bounds__(256) void k_place(const unsigned* __restrict__ ebuf,
                                               const unsigned* __restrict__ blockScan,
                                               const unsigned* __restrict__ blockSums,
                                               const unsigned* __restrict__ part,
                                               unsigned* __restrict__ csr_src) {
    __shared__ unsigned curL[256];
    int t = threadIdx.x;
    int b = blockIdx.x;
    curL[t] = 0u;
    __syncthreads();
    unsigned base = blockScan[b];
    unsigned cnt = blockSums[b];
    const unsigned* __restrict__ partB = part + b * 256;
    for (unsigned i = t; i < cnt; i += 256) {
        unsigned e = ebuf[base + i];
        unsigned s = e & 0x00FFFFFFu;
        unsigned dLow = e >> 24;
        unsigned r = atomicAdd(&curL[dLow], 1u);
        csr_src[base + partB[dLow] + r] = s;
    }
}

// --- gather: 1 wave/node; 4 edge-groups x 16 lanes; dwordx4 hb loads --------
__global__ __launch_bounds__(256) void k_gather(const uint4* __restrict__ hb4,
                                                const unsigned* __restrict__ csr_src,
                                                const unsigned* __restrict__ part,
                                                const unsigned* __restrict__ blockScan,
                                                const unsigned* __restrict__ deg,
                                                const float* __restrict__ a_src,
                                                const float* __restrict__ a_dst,
                                                const float* __restrict__ bias,
                                                float* __restrict__ out, int N) {
    int n = (int)((blockIdx.x * 256 + threadIdx.x) >> 6);
    int lane = threadIdx.x & 63;
    if (n >= N) return;
    int g = lane >> 4;        // edge group
    int L = lane & 15;        // channel block: channels 8L..8L+7
    int head = L >> 2;
    unsigned off = part[n] + blockScan[n >> 8];
    unsigned end = off + deg[n];
    float ad_n = a_dst[n * 4 + head];
    float acc[8];
#pragma unroll
    for (int i = 0; i < 8; ++i) acc[i] = 0.f;
    float dsum = 0.f;
    for (unsigned b = off; b < end; b += 8) {
        unsigned sidx = csr_src[min(b + (unsigned)(lane & 7), end - 1)];
#pragma unroll
        for (int sub = 0; sub < 2; ++sub) {
            int eidx = sub * 4 + g;
            unsigned s = (unsigned)__shfl((int)sidx, eidx);
            float as = a_src[s * 4 + head];
            uint4 u = hb4[s * 16u + (unsigned)L];
            float p = __expf(lrelu(as + ad_n));
            p = (b + (unsigned)eidx < end) ? p : 0.f;
            acc[0] = fmaf(p, __uint_as_float(u.x << 16), acc[0]);
            acc[1] = fmaf(p, __uint_as_float(u.x & 0xFFFF0000u), acc[1]);
            acc[2] = fmaf(p, __uint_as_float(u.y << 16), acc[2]);
            acc[3] = fmaf(p, __uint_as_float(u.y & 0xFFFF0000u), acc[3]);
            acc[4] = fmaf(p, __uint_as_float(u.z << 16), acc[4]);
            acc[5] = fmaf(p, __uint_as_float(u.z & 0xFFFF0000u), acc[5]);
            acc[6] = fmaf(p, __uint_as_float(u.w << 16), acc[6]);
            acc[7] = fmaf(p, __uint_as_float(u.w & 0xFFFF0000u), acc[7]);
            dsum += p;
        }
    }
    // cross-group reduction: lanes {L, L+16, L+32, L+48} hold same channels
#pragma unroll
    for (int m = 16; m <= 32; m <<= 1) {
#pragma unroll
        for (int i = 0; i < 8; ++i) acc[i] += __shfl_xor(acc[i], m);
        dsum += __shfl_xor(dsum, m);
    }
    // self loop
    float p_self = __expf(lrelu(a_src[n * 4 + head] + ad_n));
    uint4 us = hb4[(unsigned)n * 16u + (unsigned)L];
    acc[0] = fmaf(p_self, __uint_as_float(us.x << 16), acc[0]);
    acc[1] = fmaf(p_self, __uint_as_float(us.x & 0xFFFF0000u), acc[1]);
    acc[2] = fmaf(p_self, __uint_as_float(us.y << 16), acc[2]);
    acc[3] = fmaf(p_self, __uint_as_float(us.y & 0xFFFF0000u), acc[3]);
    acc[4] = fmaf(p_self, __uint_as_float(us.z << 16), acc[4]);
    acc[5] = fmaf(p_self, __uint_as_float(us.z & 0xFFFF0000u), acc[5]);
    acc[6] = fmaf(p_self, __uint_as_float(us.w << 16), acc[6]);
    acc[7] = fmaf(p_self, __uint_as_float(us.w & 0xFFFF0000u), acc[7]);
    dsum += p_self;
    float inv = 1.0f / dsum;
    if (g == 0) {
        float4 b0 = ((const float4*)bias)[L * 2];
        float4 b1 = ((const float4*)bias)[L * 2 + 1];
        float4 o0, o1;
        o0.x = acc[0] * inv + b0.x;
        o0.y = acc[1] * inv + b0.y;
        o0.z = acc[2] * inv + b0.z;
        o0.w = acc[3] * inv + b0.w;
        o1.x = acc[4] * inv + b1.x;
        o1.y = acc[5] * inv + b1.y;
        o1.z = acc[6] * inv + b1.z;
        o1.w = acc[7] * inv + b1.w;
        o0.x = o0.x > 0.f ? o0.x : (__expf(o0.x) - 1.0f);
        o0.y = o0.y > 0.f ? o0.y : (__expf(o0.y) - 1.0f);
        o0.z = o0.z > 0.f ? o0.z : (__expf(o0.z) - 1.0f);
        o0.w = o0.w > 0.f ? o0.w : (__expf(o0.w) - 1.0f);
        o1.x = o1.x > 0.f ? o1.x : (__expf(o1.x) - 1.0f);
        o1.y = o1.y > 0.f ? o1.y : (__expf(o1.y) - 1.0f);
        o1.z = o1.z > 0.f ? o1.z : (__expf(o1.z) - 1.0f);
        o1.w = o1.w > 0.f ? o1.w : (__expf(o1.w) - 1.0f);
        ((float4*)out)[(size_t)n * 32 + L * 2] = o0;
        ((float4*)out)[(size_t)n * 32 + L * 2 + 1] = o1;
    }
}

extern "C" void kernel_launch(void* const* d_in, const int* in_sizes, int n_in,
                              void* d_out, int out_size, void* d_ws, size_t ws_size,
                              hipStream_t stream) {
    const float* x = (const float*)d_in[0];
    const int* ei = (const int*)d_in[1];
    const float* W = (const float*)d_in[2];
    const float* att_src = (const float*)d_in[3];
    const float* att_dst = (const float*)d_in[4];
    const float* bias = (const float*)d_in[5];
    int N = in_sizes[0] / 128;
    int E = in_sizes[1] / 2;
    int NB = (N + 255) / 256;  // 391 buckets of 256 nodes

    char* ws = (char*)d_ws;
    size_t o = 0;
    unsigned* hb = (unsigned*)(ws + o);   o += (size_t)N * 64 * 4;   // 25.6 MB
    float* a_src = (float*)(ws + o);      o += (size_t)N * 4 * 4;
    float* a_dst = (float*)(ws + o);      o += (size_t)N * 4 * 4;
    unsigned* csr_src = (unsigned*)(ws + o); o += (size_t)E * 4;     // 6.4 MB
    unsigned* ebuf = (unsigned*)(ws + o); o += (size_t)E * 4;        // 6.4 MB
    unsigned short* Wt = (unsigned short*)(ws + o); o += 128 * 128 * 2;
    unsigned* deg = (unsigned*)(ws + o);  o += (size_t)N * 4;        // ---- zeroed region
    unsigned* gcur = (unsigned*)(ws + o); o += 2048;
    unsigned* blockScan = (unsigned*)(ws + o); o += 2048;            // ---- end zeroed
    unsigned* part = (unsigned*)(ws + o); o += (size_t)N * 4;
    unsigned* blockSums = (unsigned*)(ws + o); o += 2048;

    hipMemsetAsync(deg, 0, (size_t)N * 4 + 4096, stream);  // deg + gcur + blockScan

    k_prep<<<2048, 256, 0, stream>>>(W, ei, deg, Wt, E);
    k_scan1<<<NB, 256, 0, stream>>>(deg, part, blockSums, blockScan, N, NB);
    int EPB = 16384;
    int NBK = (E + EPB - 1) / EPB;  // 98 bucket blocks
    int nbG = (N + 127) / 128;      // 782 gemm blocks
    k_gembk<<<NBK + nbG, 512, 0, stream>>>(x, Wt, att_src, att_dst, hb, a_src, a_dst,
                                           ei, blockScan, gcur, ebuf, N, E, NB, NBK, EPB);
    k_place<<<NB, 256, 0, stream>>>(ebuf, blockScan, blockSums, part, csr_src);
    k_gather<<<(N * 64 + 255) / 256, 256, 0, stream>>>((const uint4*)hb, csr_src, part,
                                                       blockScan, deg, a_src, a_dst, bias,
                                                       (float*)d_out, N);
}